// Round 1
// baseline (2223.007 us; speedup 1.0000x reference)
//
#include <hip/hip_runtime.h>
#include <stdint.h>

#define T_STEPS 4
#define NTOK    8192
#define DMODEL  1024
#define NEXP    8
#define EFF     512
#define BM      64          // tokens per block tile
#define BN      128         // output-feature columns per block tile
#define KC      64          // K chunk staged in LDS
#define CAPTOT  (2*NTOK + NEXP*BM)   // 16896 assignment slots incl. per-expert 64-padding

// ---------------- routing ----------------

__global__ void k_count(const int* __restrict__ idx, int* __restrict__ counts) {
    int n = blockIdx.x * blockDim.x + threadIdx.x;
    if (n >= NTOK) return;
    int e0 = idx[2*n], e1 = idx[2*n+1];
    atomicAdd(&counts[e0], 1);
    if (e1 != e0) atomicAdd(&counts[e1], 1);   // dedup: duplicate top-k merges into one entry
}

__global__ void k_prefix(const int* __restrict__ counts, int* __restrict__ offsets) {
    if (threadIdx.x == 0) {
        int o = 0;
        for (int e = 0; e < NEXP; ++e) {
            offsets[e] = o;
            o += (counts[e] + BM - 1) / BM * BM;   // 64-pad each expert's region
        }
        offsets[NEXP] = o;
    }
}

__global__ void k_fill(const int* __restrict__ idx, const float* __restrict__ wts,
                       const int* __restrict__ offsets, int* __restrict__ cursors,
                       int* __restrict__ tok, float* __restrict__ wgt) {
    int n = blockIdx.x * blockDim.x + threadIdx.x;
    if (n >= NTOK) return;
    int e0 = idx[2*n], e1 = idx[2*n+1];
    float w0 = wts[2*n], w1 = wts[2*n+1];
    if (e0 == e1) w0 = __fadd_rn(w0, w1);       // same order as reference scatter-add (k=0 then k=1)
    int p0 = offsets[e0] + atomicAdd(&cursors[e0], 1);
    tok[p0] = n; wgt[p0] = w0;
    if (e1 != e0) {
        int p1 = offsets[e1] + atomicAdd(&cursors[e1], 1);
        tok[p1] = n; wgt[p1] = w1;
    }
}

// ---------------- up-proj + LIF -> spike bytes ----------------
// Block tile: BM=64 assignments x BN=128 hidden features, K=DMODEL=1024 in KC=64 chunks.
// t-loop inside; membrane state lives in registers (8x4 per thread).

__global__ __launch_bounds__(256)
void k_up(const float* __restrict__ x, const float* __restrict__ up_w,
          const int* __restrict__ offsets, const int* __restrict__ tok,
          unsigned char* __restrict__ spikes) {
    const int e  = blockIdx.z;
    const int ft = blockIdx.y;
    const int mt = blockIdx.x;
    const int base   = offsets[e];
    const int pcount = offsets[e+1] - base;
    if (mt * BM >= pcount) return;
    const int m0 = base + mt * BM;

    __shared__ float As[KC][BM + 4];   // x chunk, transposed [k][m]; +4 pad keeps 16B align
    __shared__ float Bs[KC][BN + 4];   // up_w chunk, transposed [k][f]

    const int tid = threadIdx.x;
    const int fi = tid & 31;     // 32 f-groups of 4
    const int mi = tid >> 5;     // 8 m-groups of 8

    // loader roles
    const int alm = tid & 63, alk = tid >> 6;     // A: token row, k-quarter (4 float4 each)
    const int blf = tid & 127, blk = tid >> 7;    // B: feature row, k-half   (8 float4 each)
    const int atok = tok[m0 + alm];
    const float* Bsrc = up_w + (size_t)e * EFF * DMODEL + (size_t)(ft * BN + blf) * DMODEL;

    float mem[8][4];
#pragma unroll
    for (int i = 0; i < 8; ++i)
#pragma unroll
        for (int j = 0; j < 4; ++j) mem[i][j] = 0.0f;

    for (int t = 0; t < T_STEPS; ++t) {
        float acc[8][4];
#pragma unroll
        for (int i = 0; i < 8; ++i)
#pragma unroll
            for (int j = 0; j < 4; ++j) acc[i][j] = 0.0f;

        const float* xt = x + ((size_t)t * NTOK + atok) * DMODEL;

        for (int k0 = 0; k0 < DMODEL; k0 += KC) {
            __syncthreads();
            // stage A (64 tokens x 64 k): each thread one 64B run of its token row
#pragma unroll
            for (int it = 0; it < 4; ++it) {
                int kk = alk * 16 + it * 4;
                float4 v = *(const float4*)(xt + k0 + kk);
                As[kk+0][alm] = v.x; As[kk+1][alm] = v.y;
                As[kk+2][alm] = v.z; As[kk+3][alm] = v.w;
            }
            // stage B (128 f x 64 k)
#pragma unroll
            for (int it = 0; it < 8; ++it) {
                int kk = (blk * 8 + it) * 4;
                float4 v = *(const float4*)(Bsrc + k0 + kk);
                Bs[kk+0][blf] = v.x; Bs[kk+1][blf] = v.y;
                Bs[kk+2][blf] = v.z; Bs[kk+3][blf] = v.w;
            }
            __syncthreads();
#pragma unroll 8
            for (int k = 0; k < KC; ++k) {
                const float4 a0 = *(const float4*)&As[k][mi*8];
                const float4 a1 = *(const float4*)&As[k][mi*8+4];
                const float4 bv = *(const float4*)&Bs[k][fi*4];
                float a[8] = {a0.x,a0.y,a0.z,a0.w,a1.x,a1.y,a1.z,a1.w};
                float b[4] = {bv.x,bv.y,bv.z,bv.w};
#pragma unroll
                for (int i = 0; i < 8; ++i)
#pragma unroll
                    for (int j = 0; j < 4; ++j)
                        acc[i][j] = fmaf(a[i], b[j], acc[i][j]);
            }
        }

        // LIF update (match reference rounding: mul then add, no contraction)
#pragma unroll
        for (int i = 0; i < 8; ++i) {
            uchar4 sb;
            unsigned char* sp = &sb.x;
#pragma unroll
            for (int j = 0; j < 4; ++j) {
                float m_ = __fadd_rn(__fmul_rn(0.9f, mem[i][j]), acc[i][j]);
                float s = (m_ > 1.0f) ? 1.0f : 0.0f;
                mem[i][j] = __fsub_rn(m_, s);
                sp[j] = (unsigned char)(m_ > 1.0f);
            }
            *(uchar4*)&spikes[((size_t)t * CAPTOT + (m0 + mi*8 + i)) * EFF + ft * BN + fi * 4] = sb;
        }
    }
}

// ---------------- down-proj + LIF -> weighted scatter into out ----------------
// Block tile: BM=64 assignments x BN=128 d_model columns, K=EFF=512 in KC=64 chunks.

__global__ __launch_bounds__(256)
void k_down(const unsigned char* __restrict__ spikes, const float* __restrict__ down_w,
            const int* __restrict__ offsets, const int* __restrict__ tok,
            const float* __restrict__ wgt, float* __restrict__ out) {
    const int e  = blockIdx.z;
    const int dt = blockIdx.y;
    const int mt = blockIdx.x;
    const int base   = offsets[e];
    const int pcount = offsets[e+1] - base;
    if (mt * BM >= pcount) return;
    const int m0 = base + mt * BM;

    __shared__ float As[KC][BM + 4];   // spikes chunk as floats, [k(f)][m]
    __shared__ float Bs[KC][BN + 4];   // down_w chunk, [k(f)][d]

    const int tid = threadIdx.x;
    const int fi = tid & 31;     // d-groups of 4
    const int mi = tid >> 5;

    const int lm = tid & 63, lq = tid >> 6;       // A: token row, 16-byte quarter
    const int ld = tid & 127, lq2 = tid >> 7;     // B: d row, k-half (8 float4 each)
    const float* Bsrc = down_w + (size_t)e * DMODEL * EFF + (size_t)(dt * BN + ld) * EFF;

    int   myn[8];
    float myw[8];
#pragma unroll
    for (int i = 0; i < 8; ++i) {
        int p = m0 + mi*8 + i;
        myn[i] = tok[p];
        myw[i] = wgt[p];
    }

    float mem[8][4];
#pragma unroll
    for (int i = 0; i < 8; ++i)
#pragma unroll
        for (int j = 0; j < 4; ++j) mem[i][j] = 0.0f;

    for (int t = 0; t < T_STEPS; ++t) {
        float acc[8][4];
#pragma unroll
        for (int i = 0; i < 8; ++i)
#pragma unroll
            for (int j = 0; j < 4; ++j) acc[i][j] = 0.0f;

        const unsigned char* srow = spikes + ((size_t)t * CAPTOT + (m0 + lm)) * EFF;

        for (int k0 = 0; k0 < EFF; k0 += KC) {
            __syncthreads();
            // stage A: 64 tokens x 64 spike bytes -> floats
            {
                uint4 v = *(const uint4*)(srow + k0 + lq * 16);
                unsigned vs[4] = {v.x, v.y, v.z, v.w};
#pragma unroll
                for (int q = 0; q < 4; ++q)
#pragma unroll
                    for (int j = 0; j < 4; ++j)
                        As[lq*16 + q*4 + j][lm] = (float)((vs[q] >> (8*j)) & 0xffu);
            }
            // stage B: 128 d rows x 64 f
#pragma unroll
            for (int it = 0; it < 8; ++it) {
                int kk = (lq2 * 8 + it) * 4;
                float4 v = *(const float4*)(Bsrc + k0 + kk);
                Bs[kk+0][ld] = v.x; Bs[kk+1][ld] = v.y;
                Bs[kk+2][ld] = v.z; Bs[kk+3][ld] = v.w;
            }
            __syncthreads();
#pragma unroll 8
            for (int k = 0; k < KC; ++k) {
                const float4 a0 = *(const float4*)&As[k][mi*8];
                const float4 a1 = *(const float4*)&As[k][mi*8+4];
                const float4 bv = *(const float4*)&Bs[k][fi*4];
                float a[8] = {a0.x,a0.y,a0.z,a0.w,a1.x,a1.y,a1.z,a1.w};
                float b[4] = {bv.x,bv.y,bv.z,bv.w};
#pragma unroll
                for (int i = 0; i < 8; ++i)
#pragma unroll
                    for (int j = 0; j < 4; ++j)
                        acc[i][j] = fmaf(a[i], b[j], acc[i][j]);
            }
        }

        // LIF + weighted sparse scatter (output spikes are rare -> few atomics)
#pragma unroll
        for (int i = 0; i < 8; ++i) {
#pragma unroll
            for (int j = 0; j < 4; ++j) {
                float m_ = __fadd_rn(__fmul_rn(0.9f, mem[i][j]), acc[i][j]);
                bool s = (m_ > 1.0f);
                mem[i][j] = __fsub_rn(m_, s ? 1.0f : 0.0f);
                if (s && myw[i] != 0.0f) {
                    atomicAdd(&out[((size_t)t * NTOK + myn[i]) * DMODEL + dt * BN + fi * 4 + j],
                              myw[i]);
                }
            }
        }
    }
}

// ---------------- launch ----------------

extern "C" void kernel_launch(void* const* d_in, const int* in_sizes, int n_in,
                              void* d_out, int out_size, void* d_ws, size_t ws_size,
                              hipStream_t stream) {
    const float* x      = (const float*)d_in[0];
    const int*   idx    = (const int*)  d_in[1];
    const float* wts    = (const float*)d_in[2];
    const float* up_w   = (const float*)d_in[3];
    const float* down_w = (const float*)d_in[4];
    float* out = (float*)d_out;

    char* ws = (char*)d_ws;
    int*   counts  = (int*)(ws + 0);
    int*   cursors = (int*)(ws + 32);
    int*   offsets = (int*)(ws + 64);
    int*   tok     = (int*)(ws + 128);
    float* wgt     = (float*)(ws + 128 + (size_t)CAPTOT * 4);
    unsigned char* spikes = (unsigned char*)(ws + 128 + (size_t)CAPTOT * 8);
    // ws usage: 128 + 16896*8 + 4*16896*512 bytes ~= 34.7 MB

    // zero headers + token/weight arrays (padding slots -> token 0, weight 0) and out
    hipMemsetAsync(ws, 0, 128 + (size_t)CAPTOT * 8, stream);
    hipMemsetAsync(out, 0, (size_t)out_size * sizeof(float), stream);

    k_count <<<(NTOK + 255) / 256, 256, 0, stream>>>(idx, counts);
    k_prefix<<<1, 64, 0, stream>>>(counts, offsets);
    k_fill  <<<(NTOK + 255) / 256, 256, 0, stream>>>(idx, wts, offsets, cursors, tok, wgt);

    dim3 gup(CAPTOT / BM, EFF / BN, NEXP);      // (264, 4, 8), inactive tiles early-exit
    k_up  <<<gup, 256, 0, stream>>>(x, up_w, offsets, tok, spikes);

    dim3 gdn(CAPTOT / BM, DMODEL / BN, NEXP);   // (264, 8, 8)
    k_down<<<gdn, 256, 0, stream>>>(spikes, down_w, offsets, tok, wgt, out);
}

// Round 3
// 2005.210 us; speedup vs baseline: 1.1086x; 1.1086x over previous
//
#include <hip/hip_runtime.h>
#include <stdint.h>

#define T_STEPS 4
#define NTOK    8192
#define DMODEL  1024
#define NEXP    8
#define EFF     512
#define BM      64          // tokens per block tile
#define BN      128         // output-feature columns per block tile
#define KC      32          // K chunk staged in LDS (32 -> 25.6KB LDS -> 6 blocks/CU)
#define CAPTOT  (2*NTOK + NEXP*BM)   // 16896 assignment slots incl. per-expert 64-padding

// ---------------- routing ----------------

__global__ void k_count(const int* __restrict__ idx, int* __restrict__ counts) {
    int n = blockIdx.x * blockDim.x + threadIdx.x;
    if (n >= NTOK) return;
    int e0 = idx[2*n], e1 = idx[2*n+1];
    atomicAdd(&counts[e0], 1);
    if (e1 != e0) atomicAdd(&counts[e1], 1);   // dedup: duplicate top-k merges into one entry
}

__global__ void k_prefix(const int* __restrict__ counts, int* __restrict__ offsets) {
    if (threadIdx.x == 0) {
        int o = 0;
        for (int e = 0; e < NEXP; ++e) {
            offsets[e] = o;
            o += (counts[e] + BM - 1) / BM * BM;   // 64-pad each expert's region
        }
        offsets[NEXP] = o;
    }
}

__global__ void k_fill(const int* __restrict__ idx, const float* __restrict__ wts,
                       const int* __restrict__ offsets, int* __restrict__ cursors,
                       int* __restrict__ tok, float* __restrict__ wgt) {
    int n = blockIdx.x * blockDim.x + threadIdx.x;
    if (n >= NTOK) return;
    int e0 = idx[2*n], e1 = idx[2*n+1];
    float w0 = wts[2*n], w1 = wts[2*n+1];
    if (e0 == e1) w0 = __fadd_rn(w0, w1);       // same order as reference scatter-add (k=0 then k=1)
    int p0 = offsets[e0] + atomicAdd(&cursors[e0], 1);
    tok[p0] = n; wgt[p0] = w0;
    if (e1 != e0) {
        int p1 = offsets[e1] + atomicAdd(&cursors[e1], 1);
        tok[p1] = n; wgt[p1] = w1;
    }
}

// ---------------- up-proj + LIF -> spike bytes ----------------
// Block tile: BM=64 assignments x BN=128 hidden features, K=DMODEL=1024 in KC=32 chunks.
// t-loop inside; membrane state lives in registers (8x4 per thread).

__global__ __launch_bounds__(256)
void k_up(const float* __restrict__ x, const float* __restrict__ up_w,
          const int* __restrict__ offsets, const int* __restrict__ tok,
          unsigned char* __restrict__ spikes) {
    const int e  = blockIdx.z;
    const int ft = blockIdx.y;
    const int mt = blockIdx.x;
    const int base   = offsets[e];
    const int pcount = offsets[e+1] - base;
    if (mt * BM >= pcount) return;
    const int m0 = base + mt * BM;

    __shared__ float As[KC][BM + 4];   // x chunk, transposed [k][m]; +4 pad keeps 16B align
    __shared__ float Bs[KC][BN + 4];   // up_w chunk, transposed [k][f]

    const int tid = threadIdx.x;
    const int fi = tid & 31;     // 32 f-groups of 4
    const int mi = tid >> 5;     // 8 m-groups of 8

    // loader roles
    const int alm = tid & 63, alk = tid >> 6;     // A: token row, k-eighth (2 float4 each)
    const int blf = tid & 127, blk = tid >> 7;    // B: feature row, k-half (4 float4 each)
    const int atok = tok[m0 + alm];
    const float* Bsrc = up_w + (size_t)e * EFF * DMODEL + (size_t)(ft * BN + blf) * DMODEL;

    float mem[8][4];
#pragma unroll
    for (int i = 0; i < 8; ++i)
#pragma unroll
        for (int j = 0; j < 4; ++j) mem[i][j] = 0.0f;

    for (int t = 0; t < T_STEPS; ++t) {
        float acc[8][4];
#pragma unroll
        for (int i = 0; i < 8; ++i)
#pragma unroll
            for (int j = 0; j < 4; ++j) acc[i][j] = 0.0f;

        const float* xt = x + ((size_t)t * NTOK + atok) * DMODEL;

        for (int k0 = 0; k0 < DMODEL; k0 += KC) {
            __syncthreads();
            // stage A (64 tokens x 32 k): each thread two float4 of its token row
#pragma unroll
            for (int it = 0; it < 2; ++it) {
                int kk = alk * 8 + it * 4;
                float4 v = *(const float4*)(xt + k0 + kk);
                As[kk+0][alm] = v.x; As[kk+1][alm] = v.y;
                As[kk+2][alm] = v.z; As[kk+3][alm] = v.w;
            }
            // stage B (128 f x 32 k): four float4 per thread
#pragma unroll
            for (int it = 0; it < 4; ++it) {
                int kk = blk * 16 + it * 4;
                float4 v = *(const float4*)(Bsrc + k0 + kk);
                Bs[kk+0][blf] = v.x; Bs[kk+1][blf] = v.y;
                Bs[kk+2][blf] = v.z; Bs[kk+3][blf] = v.w;
            }
            __syncthreads();
#pragma unroll 8
            for (int k = 0; k < KC; ++k) {
                const float4 a0 = *(const float4*)&As[k][mi*8];
                const float4 a1 = *(const float4*)&As[k][mi*8+4];
                const float4 bv = *(const float4*)&Bs[k][fi*4];
                float a[8] = {a0.x,a0.y,a0.z,a0.w,a1.x,a1.y,a1.z,a1.w};
                float b[4] = {bv.x,bv.y,bv.z,bv.w};
#pragma unroll
                for (int i = 0; i < 8; ++i)
#pragma unroll
                    for (int j = 0; j < 4; ++j)
                        acc[i][j] = fmaf(a[i], b[j], acc[i][j]);
            }
        }

        // LIF update (match reference rounding: mul then add, no contraction)
#pragma unroll
        for (int i = 0; i < 8; ++i) {
            uchar4 sb;
            unsigned char* sp = &sb.x;
#pragma unroll
            for (int j = 0; j < 4; ++j) {
                float m_ = __fadd_rn(__fmul_rn(0.9f, mem[i][j]), acc[i][j]);
                float s = (m_ > 1.0f) ? 1.0f : 0.0f;
                mem[i][j] = __fsub_rn(m_, s);
                sp[j] = (unsigned char)(m_ > 1.0f);
            }
            *(uchar4*)&spikes[((size_t)t * CAPTOT + (m0 + mi*8 + i)) * EFF + ft * BN + fi * 4] = sb;
        }
    }
}

// ---------------- down-proj + LIF -> weighted scatter into out ----------------
// Block tile: BM=64 assignments x BN=128 d_model columns, K=EFF=512 in KC=32 chunks.

__global__ __launch_bounds__(256)
void k_down(const unsigned char* __restrict__ spikes, const float* __restrict__ down_w,
            const int* __restrict__ offsets, const int* __restrict__ tok,
            const float* __restrict__ wgt, float* __restrict__ out) {
    const int e  = blockIdx.z;
    const int dt = blockIdx.y;
    const int mt = blockIdx.x;
    const int base   = offsets[e];
    const int pcount = offsets[e+1] - base;
    if (mt * BM >= pcount) return;
    const int m0 = base + mt * BM;

    __shared__ float As[KC][BM + 4];   // spikes chunk as floats, [k(f)][m]
    __shared__ float Bs[KC][BN + 4];   // down_w chunk, [k(f)][d]

    const int tid = threadIdx.x;
    const int fi = tid & 31;     // d-groups of 4
    const int mi = tid >> 5;

    const int lm = tid & 63, lq = tid >> 6;       // A: token row, 8-byte chunk of 32
    const int ld = tid & 127, lq2 = tid >> 7;     // B: d row, k-half (4 float4 each)
    const float* Bsrc = down_w + (size_t)e * DMODEL * EFF + (size_t)(dt * BN + ld) * EFF;

    int   myn[8];
    float myw[8];
#pragma unroll
    for (int i = 0; i < 8; ++i) {
        int p = m0 + mi*8 + i;
        myn[i] = tok[p];
        myw[i] = wgt[p];
    }

    float mem[8][4];
#pragma unroll
    for (int i = 0; i < 8; ++i)
#pragma unroll
        for (int j = 0; j < 4; ++j) mem[i][j] = 0.0f;

    for (int t = 0; t < T_STEPS; ++t) {
        float acc[8][4];
#pragma unroll
        for (int i = 0; i < 8; ++i)
#pragma unroll
            for (int j = 0; j < 4; ++j) acc[i][j] = 0.0f;

        const unsigned char* srow = spikes + ((size_t)t * CAPTOT + (m0 + lm)) * EFF;

        for (int k0 = 0; k0 < EFF; k0 += KC) {
            __syncthreads();
            // stage A: 64 tokens x 32 spike bytes -> floats (8 bytes per thread)
            {
                uint2 v = *(const uint2*)(srow + k0 + lq * 8);
                unsigned vs[2] = {v.x, v.y};
#pragma unroll
                for (int q = 0; q < 2; ++q)
#pragma unroll
                    for (int j = 0; j < 4; ++j)
                        As[lq*8 + q*4 + j][lm] = (float)((vs[q] >> (8*j)) & 0xffu);
            }
            // stage B: 128 d rows x 32 f
#pragma unroll
            for (int it = 0; it < 4; ++it) {
                int kk = lq2 * 16 + it * 4;
                float4 v = *(const float4*)(Bsrc + k0 + kk);
                Bs[kk+0][ld] = v.x; Bs[kk+1][ld] = v.y;
                Bs[kk+2][ld] = v.z; Bs[kk+3][ld] = v.w;
            }
            __syncthreads();
#pragma unroll 8
            for (int k = 0; k < KC; ++k) {
                const float4 a0 = *(const float4*)&As[k][mi*8];
                const float4 a1 = *(const float4*)&As[k][mi*8+4];
                const float4 bv = *(const float4*)&Bs[k][fi*4];
                float a[8] = {a0.x,a0.y,a0.z,a0.w,a1.x,a1.y,a1.z,a1.w};
                float b[4] = {bv.x,bv.y,bv.z,bv.w};
#pragma unroll
                for (int i = 0; i < 8; ++i)
#pragma unroll
                    for (int j = 0; j < 4; ++j)
                        acc[i][j] = fmaf(a[i], b[j], acc[i][j]);
            }
        }

        // LIF + weighted sparse scatter (output spikes are rare -> few atomics)
#pragma unroll
        for (int i = 0; i < 8; ++i) {
#pragma unroll
            for (int j = 0; j < 4; ++j) {
                float m_ = __fadd_rn(__fmul_rn(0.9f, mem[i][j]), acc[i][j]);
                bool s = (m_ > 1.0f);
                mem[i][j] = __fsub_rn(m_, s ? 1.0f : 0.0f);
                if (s && myw[i] != 0.0f) {
                    atomicAdd(&out[((size_t)t * NTOK + myn[i]) * DMODEL + dt * BN + fi * 4 + j],
                              myw[i]);
                }
            }
        }
    }
}

// ---------------- launch ----------------

extern "C" void kernel_launch(void* const* d_in, const int* in_sizes, int n_in,
                              void* d_out, int out_size, void* d_ws, size_t ws_size,
                              hipStream_t stream) {
    const float* x      = (const float*)d_in[0];
    const int*   idx    = (const int*)  d_in[1];
    const float* wts    = (const float*)d_in[2];
    const float* up_w   = (const float*)d_in[3];
    const float* down_w = (const float*)d_in[4];
    float* out = (float*)d_out;

    char* ws = (char*)d_ws;
    int*   counts  = (int*)(ws + 0);
    int*   cursors = (int*)(ws + 32);
    int*   offsets = (int*)(ws + 64);
    int*   tok     = (int*)(ws + 128);
    float* wgt     = (float*)(ws + 128 + (size_t)CAPTOT * 4);
    unsigned char* spikes = (unsigned char*)(ws + 128 + (size_t)CAPTOT * 8);
    // ws usage: 128 + 16896*8 + 4*16896*512 bytes ~= 34.7 MB

    // zero headers + token/weight arrays (padding slots -> token 0, weight 0) and out
    hipMemsetAsync(ws, 0, 128 + (size_t)CAPTOT * 8, stream);
    hipMemsetAsync(out, 0, (size_t)out_size * sizeof(float), stream);

    k_count <<<(NTOK + 255) / 256, 256, 0, stream>>>(idx, counts);
    k_prefix<<<1, 64, 0, stream>>>(counts, offsets);
    k_fill  <<<(NTOK + 255) / 256, 256, 0, stream>>>(idx, wts, offsets, cursors, tok, wgt);

    dim3 gup(CAPTOT / BM, EFF / BN, NEXP);      // (264, 4, 8), inactive tiles early-exit
    k_up  <<<gup, 256, 0, stream>>>(x, up_w, offsets, tok, spikes);

    dim3 gdn(CAPTOT / BM, DMODEL / BN, NEXP);   // (264, 8, 8)
    k_down<<<gdn, 256, 0, stream>>>(spikes, down_w, offsets, tok, wgt, out);
}

// Round 4
// 1052.623 us; speedup vs baseline: 2.1119x; 1.9050x over previous
//
#include <hip/hip_runtime.h>
#include <stdint.h>

#define T_STEPS 4
#define NTOK    8192
#define DMODEL  1024
#define NEXP    8
#define EFF     512
#define BMT     128                      // block tile rows (tokens); expert regions padded to 128
#define CAPTOT  (2*NTOK + NEXP*BMT)      // 17408 assignment slots incl. per-expert padding

typedef __attribute__((ext_vector_type(8))) short bf8_t;   // 8 bf16 (4 VGPRs) MFMA operand
typedef __attribute__((ext_vector_type(4))) float f32x4;   // MFMA accumulator

#define MFMA(a,b,c) __builtin_amdgcn_mfma_f32_16x16x32_bf16((a),(b),(c),0,0,0)

// ---------------- bf16 3-limb split helpers ----------------

__device__ __forceinline__ unsigned short bf16rn(float f) {
    unsigned u = __float_as_uint(f);
    unsigned r = u + 0x7fffu + ((u >> 16) & 1u);   // round-to-nearest-even
    return (unsigned short)(r >> 16);
}
__device__ __forceinline__ float bf2f(unsigned short h) {
    return __uint_as_float(((unsigned)h) << 16);
}
__device__ __forceinline__ unsigned pk(unsigned short a, unsigned short b) {
    return (unsigned)a | ((unsigned)b << 16);
}

// read 8 floats from src, split into 3 bf16 limbs, write 16B per limb to LDS
__device__ __forceinline__ void stage8_3limb(const float* __restrict__ src,
                                             unsigned short* d0, unsigned short* d1,
                                             unsigned short* d2) {
    float v[8];
    *(float4*)&v[0] = *(const float4*)(src + 0);
    *(float4*)&v[4] = *(const float4*)(src + 4);
    unsigned short h[8], m[8], l[8];
#pragma unroll
    for (int i = 0; i < 8; ++i) {
        unsigned short a = bf16rn(v[i]);
        float r1 = v[i] - bf2f(a);
        unsigned short b = bf16rn(r1);
        float r2 = r1 - bf2f(b);
        h[i] = a; m[i] = b; l[i] = bf16rn(r2);
    }
    *(uint4*)d0 = make_uint4(pk(h[0],h[1]), pk(h[2],h[3]), pk(h[4],h[5]), pk(h[6],h[7]));
    *(uint4*)d1 = make_uint4(pk(m[0],m[1]), pk(m[2],m[3]), pk(m[4],m[5]), pk(m[6],m[7]));
    *(uint4*)d2 = make_uint4(pk(l[0],l[1]), pk(l[2],l[3]), pk(l[4],l[5]), pk(l[6],l[7]));
}

// ---------------- routing ----------------

__global__ void k_count(const int* __restrict__ idx, int* __restrict__ counts) {
    int n = blockIdx.x * blockDim.x + threadIdx.x;
    if (n >= NTOK) return;
    int e0 = idx[2*n], e1 = idx[2*n+1];
    atomicAdd(&counts[e0], 1);
    if (e1 != e0) atomicAdd(&counts[e1], 1);   // dedup duplicate top-k
}

__global__ void k_prefix(const int* __restrict__ counts, int* __restrict__ offsets) {
    if (threadIdx.x == 0) {
        int o = 0;
        for (int e = 0; e < NEXP; ++e) {
            offsets[e] = o;
            o += (counts[e] + BMT - 1) / BMT * BMT;   // pad each expert region to 128
        }
        offsets[NEXP] = o;
    }
}

__global__ void k_fill(const int* __restrict__ idx, const float* __restrict__ wts,
                       const int* __restrict__ offsets, int* __restrict__ cursors,
                       int* __restrict__ tok, float* __restrict__ wgt) {
    int n = blockIdx.x * blockDim.x + threadIdx.x;
    if (n >= NTOK) return;
    int e0 = idx[2*n], e1 = idx[2*n+1];
    float w0 = wts[2*n], w1 = wts[2*n+1];
    if (e0 == e1) w0 = __fadd_rn(w0, w1);      // reference scatter-add order
    int p0 = offsets[e0] + atomicAdd(&cursors[e0], 1);
    tok[p0] = n; wgt[p0] = w0;
    if (e1 != e0) {
        int p1 = offsets[e1] + atomicAdd(&cursors[e1], 1);
        tok[p1] = n; wgt[p1] = w1;
    }
}

// ---------------- up-proj (3-limb bf16 MFMA) + fused LIF -> bf16 spikes ----------------
// Block: 128 tokens x 128 features, K=1024 in 32-chunks. 4 waves, each 64x64 (4x4 MFMA tiles).
// 6 limb products per tile per chunk. Membrane in registers (C-layout), t-loop outer.

__global__ __launch_bounds__(256, 2)
void k_up(const float* __restrict__ x, const float* __restrict__ up_w,
          const int* __restrict__ offsets, const int* __restrict__ tok,
          unsigned short* __restrict__ spk) {
    const int m0 = blockIdx.x * BMT;
    const int ft = blockIdx.y;
    if (m0 >= offsets[NEXP]) return;
    int e = 0;
    for (int i = 1; i < NEXP; ++i) if (m0 >= offsets[i]) e = i;

    __shared__ unsigned short As[3][128][40];   // [limb][token][k], +8 pad (80B stride -> 2-way frag reads)
    __shared__ unsigned short Bs[3][128][40];   // [limb][feature][k]

    const int tid  = threadIdx.x;
    const int lane = tid & 63, wid = tid >> 6;
    const int quad = lane >> 4, l16 = lane & 15;
    const int mw = (wid & 1) * 64, nw = (wid >> 1) * 64;

    // staging roles: thread -> row r (0..127), 16-elem half
    const int r = tid >> 1, half = tid & 1;
    const int tokA = tok[m0 + r];
    const float* xbase = x + (size_t)tokA * DMODEL + half * 16;
    const float* wrow  = up_w + ((size_t)e * EFF + ft * 128 + r) * DMODEL + half * 16;

    f32x4 mem[4][4];
#pragma unroll
    for (int i = 0; i < 4; ++i)
#pragma unroll
        for (int j = 0; j < 4; ++j) mem[i][j] = (f32x4){0.f,0.f,0.f,0.f};

    for (int t = 0; t < T_STEPS; ++t) {
        f32x4 acc[4][4];
#pragma unroll
        for (int i = 0; i < 4; ++i)
#pragma unroll
            for (int j = 0; j < 4; ++j) acc[i][j] = (f32x4){0.f,0.f,0.f,0.f};

        const float* xrow = xbase + (size_t)t * NTOK * DMODEL;

        for (int kc = 0; kc < DMODEL; kc += 32) {
            __syncthreads();
            stage8_3limb(xrow + kc,     &As[0][r][half*16],   &As[1][r][half*16],   &As[2][r][half*16]);
            stage8_3limb(xrow + kc + 8, &As[0][r][half*16+8], &As[1][r][half*16+8], &As[2][r][half*16+8]);
            stage8_3limb(wrow + kc,     &Bs[0][r][half*16],   &Bs[1][r][half*16],   &Bs[2][r][half*16]);
            stage8_3limb(wrow + kc + 8, &Bs[0][r][half*16+8], &Bs[1][r][half*16+8], &Bs[2][r][half*16+8]);
            __syncthreads();

            bf8_t bh[4], bm[4], bl[4];
#pragma unroll
            for (int nt = 0; nt < 4; ++nt) {
                const int nr = nw + nt*16 + l16;
                bh[nt] = *(const bf8_t*)&Bs[0][nr][quad*8];
                bm[nt] = *(const bf8_t*)&Bs[1][nr][quad*8];
                bl[nt] = *(const bf8_t*)&Bs[2][nr][quad*8];
            }
#pragma unroll
            for (int mt = 0; mt < 4; ++mt) {
                const int mr = mw + mt*16 + l16;
                bf8_t ah = *(const bf8_t*)&As[0][mr][quad*8];
                bf8_t am = *(const bf8_t*)&As[1][mr][quad*8];
                bf8_t al = *(const bf8_t*)&As[2][mr][quad*8];
#pragma unroll
                for (int nt = 0; nt < 4; ++nt) {
                    f32x4 c = acc[mt][nt];
                    c = MFMA(ah, bh[nt], c);
                    c = MFMA(am, bh[nt], c);
                    c = MFMA(ah, bm[nt], c);
                    c = MFMA(am, bm[nt], c);
                    c = MFMA(al, bh[nt], c);
                    c = MFMA(ah, bl[nt], c);
                    acc[mt][nt] = c;
                }
            }
        }

        // fused LIF epilogue (C layout: row = quad*4+reg, col = l16)
#pragma unroll
        for (int mt = 0; mt < 4; ++mt)
#pragma unroll
            for (int nt = 0; nt < 4; ++nt)
#pragma unroll
                for (int reg = 0; reg < 4; ++reg) {
                    float mv = __fadd_rn(__fmul_rn(0.9f, mem[mt][nt][reg]), acc[mt][nt][reg]);
                    bool s = mv > 1.0f;
                    mem[mt][nt][reg] = __fsub_rn(mv, s ? 1.0f : 0.0f);
                    int row = m0 + mw + mt*16 + quad*4 + reg;
                    int col = ft*128 + nw + nt*16 + l16;
                    spk[((size_t)t * CAPTOT + row) * EFF + col] = s ? 0x3F80u : 0u;
                }
    }
}

// ---------------- down-proj (spikes exact bf16 x 3-limb weights) + fused LIF + scatter ----------------
// Block: 128 tokens x 64 d_model cols, K=512 in 32-chunks. 4 waves, each 64x32 (4x2 tiles).

__global__ __launch_bounds__(256, 3)
void k_dn(const unsigned short* __restrict__ spk, const float* __restrict__ down_w,
          const int* __restrict__ offsets, const int* __restrict__ tok,
          const float* __restrict__ wgt, float* __restrict__ out) {
    const int m0 = blockIdx.x * BMT;
    const int dt = blockIdx.y;
    if (m0 >= offsets[NEXP]) return;
    int e = 0;
    for (int i = 1; i < NEXP; ++i) if (m0 >= offsets[i]) e = i;

    __shared__ unsigned short As[128][40];      // spikes [token][k(f)]
    __shared__ unsigned short Bs[3][64][40];    // weights [limb][d][k(f)]

    const int tid  = threadIdx.x;
    const int lane = tid & 63, wid = tid >> 6;
    const int quad = lane >> 4, l16 = lane & 15;
    const int mw = (wid & 1) * 64, nw = (wid >> 1) * 32;

    const int r = tid >> 1, half = tid & 1;       // A stager: row, 16-elem half
    const int dr = tid >> 2, q = tid & 3;         // B stager: d-row, 8-elem quarter
    const unsigned short* arow = spk + (size_t)(m0 + r) * EFF + half * 16;
    const float* brow = down_w + ((size_t)e * DMODEL + dt * 64 + dr) * EFF + q * 8;

    // row metadata for epilogue scatter
    int   rn[4][4];
    float rw[4][4];
#pragma unroll
    for (int mt = 0; mt < 4; ++mt)
#pragma unroll
        for (int reg = 0; reg < 4; ++reg) {
            int rr = m0 + mw + mt*16 + quad*4 + reg;
            rn[mt][reg] = tok[rr];
            rw[mt][reg] = wgt[rr];
        }

    f32x4 mem[4][2];
#pragma unroll
    for (int i = 0; i < 4; ++i) { mem[i][0] = (f32x4){0.f,0.f,0.f,0.f}; mem[i][1] = (f32x4){0.f,0.f,0.f,0.f}; }

    for (int t = 0; t < T_STEPS; ++t) {
        f32x4 acc[4][2];
#pragma unroll
        for (int i = 0; i < 4; ++i) { acc[i][0] = (f32x4){0.f,0.f,0.f,0.f}; acc[i][1] = (f32x4){0.f,0.f,0.f,0.f}; }

        const unsigned short* at = arow + (size_t)t * CAPTOT * EFF;

        for (int kc = 0; kc < EFF; kc += 32) {
            __syncthreads();
            *(uint4*)&As[r][half*16 + 0] = *(const uint4*)(at + kc + 0);
            *(uint4*)&As[r][half*16 + 8] = *(const uint4*)(at + kc + 8);
            stage8_3limb(brow + kc, &Bs[0][dr][q*8], &Bs[1][dr][q*8], &Bs[2][dr][q*8]);
            __syncthreads();

            bf8_t bh[2], bm[2], bl[2];
#pragma unroll
            for (int nt = 0; nt < 2; ++nt) {
                const int nr = nw + nt*16 + l16;
                bh[nt] = *(const bf8_t*)&Bs[0][nr][quad*8];
                bm[nt] = *(const bf8_t*)&Bs[1][nr][quad*8];
                bl[nt] = *(const bf8_t*)&Bs[2][nr][quad*8];
            }
#pragma unroll
            for (int mt = 0; mt < 4; ++mt) {
                const int mr = mw + mt*16 + l16;
                bf8_t a = *(const bf8_t*)&As[mr][quad*8];
#pragma unroll
                for (int nt = 0; nt < 2; ++nt) {
                    f32x4 c = acc[mt][nt];
                    c = MFMA(a, bh[nt], c);
                    c = MFMA(a, bm[nt], c);
                    c = MFMA(a, bl[nt], c);
                    acc[mt][nt] = c;
                }
            }
        }

        // fused LIF + weighted sparse scatter
#pragma unroll
        for (int mt = 0; mt < 4; ++mt)
#pragma unroll
            for (int nt = 0; nt < 2; ++nt)
#pragma unroll
                for (int reg = 0; reg < 4; ++reg) {
                    float mv = __fadd_rn(__fmul_rn(0.9f, mem[mt][nt][reg]), acc[mt][nt][reg]);
                    bool s = mv > 1.0f;
                    mem[mt][nt][reg] = __fsub_rn(mv, s ? 1.0f : 0.0f);
                    float w = rw[mt][reg];
                    if (s && w != 0.0f) {
                        int col = dt*64 + nw + nt*16 + l16;
                        atomicAdd(out + ((size_t)t * NTOK + rn[mt][reg]) * DMODEL + col, w);
                    }
                }
    }
}

// ---------------- launch ----------------

extern "C" void kernel_launch(void* const* d_in, const int* in_sizes, int n_in,
                              void* d_out, int out_size, void* d_ws, size_t ws_size,
                              hipStream_t stream) {
    const float* x      = (const float*)d_in[0];
    const int*   idx    = (const int*)  d_in[1];
    const float* wts    = (const float*)d_in[2];
    const float* up_w   = (const float*)d_in[3];
    const float* down_w = (const float*)d_in[4];
    float* out = (float*)d_out;

    char* ws = (char*)d_ws;
    int*   counts  = (int*)(ws + 0);
    int*   cursors = (int*)(ws + 32);
    int*   offsets = (int*)(ws + 64);
    int*   tok     = (int*)(ws + 128);
    float* wgt     = (float*)(ws + 128 + (size_t)CAPTOT * 4);
    unsigned short* spk = (unsigned short*)(ws + 128 + (size_t)CAPTOT * 8);
    // ws: 128 + 17408*8 + 4*17408*512*2 B  ~= 71.4 MB

    hipMemsetAsync(ws, 0, 128 + (size_t)CAPTOT * 8, stream);
    hipMemsetAsync(out, 0, (size_t)out_size * sizeof(float), stream);

    k_count <<<(NTOK + 255) / 256, 256, 0, stream>>>(idx, counts);
    k_prefix<<<1, 64, 0, stream>>>(counts, offsets);
    k_fill  <<<(NTOK + 255) / 256, 256, 0, stream>>>(idx, wts, offsets, cursors, tok, wgt);

    dim3 gup(CAPTOT / BMT, EFF / 128);      // (136, 4); tiles past used rows early-exit
    k_up<<<gup, 256, 0, stream>>>(x, up_w, offsets, tok, spk);

    dim3 gdn(CAPTOT / BMT, DMODEL / 64);    // (136, 16)
    k_dn<<<gdn, 256, 0, stream>>>(spk, down_w, offsets, tok, wgt, out);
}